// Round 4
// baseline (796.126 us; speedup 1.0000x reference)
//
#include <hip/hip_runtime.h>
#include <math.h>

#define D 4096
#define F 384
#define NB 32
#define NG 196
#define NL 36
#define SROWS 21760
#define TROWS 12544
#define TCHUNK 6272   /* 32*196 teacher-region rows per i-chunk */
#define LCHUNK 1152   /* 32*36 student local-chunk rows */
#define NPART (SROWS + 576)
#define KT 32         /* k-tile for sim GEMM */
#define PADW 68       /* padded LDS row width (words), 16B-aligned */

// ---------- helpers ----------
__device__ inline float get_invtemp(const int* ep_ptr) {
  int ep = *ep_ptr;
  double t = (ep < 30) ? (0.04 + (double)ep * (0.03 / 29.0)) : 0.07;
  return 1.0f / (float)t;
}

__device__ inline float warp_max(float v) {
#pragma unroll
  for (int o = 32; o; o >>= 1) v = fmaxf(v, __shfl_xor(v, o));
  return v;
}
__device__ inline float warp_sum(float v) {
#pragma unroll
  for (int o = 32; o; o >>= 1) v += __shfl_xor(v, o);
  return v;
}
// 256-thread (4-wave) block reductions; sc is 8-float LDS scratch.
__device__ inline float block_max(float v, float* sc) {
  v = warp_max(v);
  __syncthreads();
  if ((threadIdx.x & 63) == 0) sc[threadIdx.x >> 6] = v;
  __syncthreads();
  return fmaxf(fmaxf(sc[0], sc[1]), fmaxf(sc[2], sc[3]));
}
__device__ inline float block_sum(float v, float* sc) {
  v = warp_sum(v);
  __syncthreads();
  if ((threadIdx.x & 63) == 0) sc[threadIdx.x >> 6] = v;
  __syncthreads();
  return (sc[0] + sc[1]) + (sc[2] + sc[3]);
}
// two simultaneous block sums sharing one barrier pair
__device__ inline void block_sum2(float a, float b, float* sc, float* ra, float* rb) {
#pragma unroll
  for (int o = 32; o; o >>= 1) { a += __shfl_xor(a, o); b += __shfl_xor(b, o); }
  __syncthreads();
  if ((threadIdx.x & 63) == 0) {
    sc[threadIdx.x >> 6] = a;
    sc[4 + (threadIdx.x >> 6)] = b;
  }
  __syncthreads();
  *ra = (sc[0] + sc[1]) + (sc[2] + sc[3]);
  *rb = (sc[4] + sc[5]) + (sc[6] + sc[7]);
}

__device__ inline unsigned long long umax64(unsigned long long a, unsigned long long b) {
  return a > b ? a : b;
}
// monotone float->u32, then pack with inverted idx so equal keys prefer SMALLER idx (first-max, like jnp.argmax)
__device__ inline unsigned long long pack_key(float sim, int tc) {
  unsigned bts = __float_as_uint(sim);
  bts = (bts & 0x80000000u) ? ~bts : (bts | 0x80000000u);
  return ((unsigned long long)bts << 32) | (unsigned long long)(0xFFFFFFFFu - (unsigned)tc);
}
__device__ inline void unpack4(float4 v, float* dst) {
  dst[0] = v.x; dst[1] = v.y; dst[2] = v.z; dst[3] = v.w;
}

// student-region global row for (cat, b, tile position p)
// cat 0: j=0 rows; cat 1: j=1 rows; cat 2: packed locals p in [0,288)
__device__ inline int srow_of(int cat, int b, int p) {
  if (cat == 0) return b * NG + p;
  if (cat == 1) return TCHUNK + b * NG + p;
  int j = p / 36;           // 0..7 -> actual crop j-2
  int pos = p - j * 36;
  return 2 * TCHUNK + j * LCHUNK + b * NL + pos;
}

// ---------- K1: teacher feat inverse norms ----------
__global__ __launch_bounds__(256) void k_tnorm(const float* __restrict__ tfea,
                                               float* __restrict__ invtn) {
  int gw = (blockIdx.x * 256 + threadIdx.x) >> 6;  // one wave per row
  int lane = threadIdx.x & 63;
  if (gw >= TROWS) return;
  const float* p = tfea + (size_t)gw * F;
  float ss = 0.f;
#pragma unroll
  for (int k = 0; k < 6; k++) { float v = p[lane + 64 * k]; ss += v * v; }
  ss = warp_sum(ss);
  if (lane == 0) invtn[gw] = 1.0f / fmaxf(sqrtf(ss), 1e-12f);
}

// ---------- K1b: teacher-region softmax stats (max, sumexp) per row ----------
__global__ __launch_bounds__(256) void k_tstat(const float* __restrict__ treg,
                                               const float* __restrict__ cgrid,
                                               const int* __restrict__ epoch,
                                               float2* __restrict__ tstat) {
  __shared__ float sc[8];
  int r = blockIdx.x, tid = threadIdx.x;
  float invt = get_invtemp(epoch);
  const float4* tp = (const float4*)(treg + (size_t)r * D);
  const float4* cp = (const float4*)cgrid;
  float tv[16], cv[16];
  unpack4(tp[tid], tv); unpack4(tp[tid + 256], tv + 4);
  unpack4(tp[tid + 512], tv + 8); unpack4(tp[tid + 768], tv + 12);
  unpack4(cp[tid], cv); unpack4(cp[tid + 256], cv + 4);
  unpack4(cp[tid + 512], cv + 8); unpack4(cp[tid + 768], cv + 12);
#pragma unroll
  for (int k = 0; k < 16; k++) tv[k] = (tv[k] - cv[k]) * invt;
  float m = -INFINITY;
#pragma unroll
  for (int k = 0; k < 16; k++) m = fmaxf(m, tv[k]);
  float Tm = block_max(m, sc);
  float e = 0.f;
#pragma unroll
  for (int k = 0; k < 16; k++) e += expf(tv[k] - Tm);
  float es = block_sum(e, sc);
  if (tid == 0) tstat[r] = make_float2(Tm, es);
}

// ---------- K2: cosine-sim GEMM + fused argmax (K-major LDS, uniform dual-acc) ----------
// grid: 32 b * 36 tiles = 1152 blocks.
// per b: w<16 -> globals: cat=w>>3 (j), st=(w&7)>>1, tt=(w&7)&1; planes A/B = two 64-col tiles of SAME teacher
//        w>=16 -> locals: st=(w-16)>>2, tt=(w-16)&3; planes A/B = teacher i=0 / i=1, same cols
__global__ __launch_bounds__(256) void k_sim(const float* __restrict__ sfea,
                                             const float* __restrict__ tfea,
                                             const float* __restrict__ invtn,
                                             unsigned long long* __restrict__ keys) {
  __shared__ float s_km[KT][PADW];
  __shared__ float tA_km[KT][PADW];
  __shared__ float tB_km[KT][PADW];
  int tid = threadIdx.x;
  int bid = blockIdx.x;
  int w = bid % 36, b = bid / 36;
  int cat, base_p, tcA0, tcB0, iA;
  if (w < 16) {
    cat = w >> 3;
    int rest = w & 7;
    base_p = (rest >> 1) * 64;
    int tt = rest & 1;
    tcA0 = tt * 128; tcB0 = tt * 128 + 64;
    iA = (cat == 0) ? 1 : 0;
  } else {
    int w2 = w - 16;
    cat = 2;
    base_p = (w2 >> 2) * 64;
    int tt = w2 & 3;
    tcA0 = tt * 64; tcB0 = tt * 64;
    iA = 0;
  }
  int vs = ((cat < 2) ? NG : 288) - base_p; if (vs > 64) vs = 64;
  int vtA = NG - tcA0; if (vtA > 64) vtA = 64;
  int vtB = NG - tcB0; if (vtB > 64) vtB = 64;  // globals tt=1: 4
  int gA = iA * TCHUNK + b * NG + tcA0;
  int gB = ((cat < 2) ? iA : 1) * TCHUNK + b * NG + tcB0;
  int tx = tid & 15, ty = tid >> 4;

  // fixed per-thread load slots: rows (row0, row0+32), k-group c4
  int row0 = tid >> 3, c4 = tid & 7;
  int row1 = row0 + 32;
  bool sv0 = row0 < vs, sv1 = row1 < vs;
  bool av0 = row0 < vtA, av1 = row1 < vtA;
  bool bv0 = row0 < vtB, bv1 = row1 < vtB;
  const float* sp0 = sfea + (size_t)srow_of(cat, b, base_p + (sv0 ? row0 : 0)) * F + c4 * 4;
  const float* sp1 = sfea + (size_t)srow_of(cat, b, base_p + (sv1 ? row1 : 0)) * F + c4 * 4;
  const float* tpA0 = tfea + (size_t)(gA + (av0 ? row0 : 0)) * F + c4 * 4;
  const float* tpA1 = tfea + (size_t)(gA + (av1 ? row1 : 0)) * F + c4 * 4;
  const float* tpB0 = tfea + (size_t)(gB + (bv0 ? row0 : 0)) * F + c4 * 4;
  const float* tpB1 = tfea + (size_t)(gB + (bv1 ? row1 : 0)) * F + c4 * 4;
  int kbase = c4 * 4;

  float accA[4][4] = {{0.f}}, accB[4][4] = {{0.f}};
  const float4 z4 = make_float4(0.f, 0.f, 0.f, 0.f);

  for (int kt = 0; kt < F / KT; kt++) {
    int k0 = kt * KT;
    float4 a0 = sv0 ? *(const float4*)(sp0 + k0) : z4;
    float4 a1 = sv1 ? *(const float4*)(sp1 + k0) : z4;
    float4 b0 = av0 ? *(const float4*)(tpA0 + k0) : z4;
    float4 b1 = av1 ? *(const float4*)(tpA1 + k0) : z4;
    float4 d0 = bv0 ? *(const float4*)(tpB0 + k0) : z4;
    float4 d1 = bv1 ? *(const float4*)(tpB1 + k0) : z4;
    __syncthreads();
    s_km[kbase + 0][row0] = a0.x; s_km[kbase + 1][row0] = a0.y;
    s_km[kbase + 2][row0] = a0.z; s_km[kbase + 3][row0] = a0.w;
    s_km[kbase + 0][row1] = a1.x; s_km[kbase + 1][row1] = a1.y;
    s_km[kbase + 2][row1] = a1.z; s_km[kbase + 3][row1] = a1.w;
    tA_km[kbase + 0][row0] = b0.x; tA_km[kbase + 1][row0] = b0.y;
    tA_km[kbase + 2][row0] = b0.z; tA_km[kbase + 3][row0] = b0.w;
    tA_km[kbase + 0][row1] = b1.x; tA_km[kbase + 1][row1] = b1.y;
    tA_km[kbase + 2][row1] = b1.z; tA_km[kbase + 3][row1] = b1.w;
    tB_km[kbase + 0][row0] = d0.x; tB_km[kbase + 1][row0] = d0.y;
    tB_km[kbase + 2][row0] = d0.z; tB_km[kbase + 3][row0] = d0.w;
    tB_km[kbase + 0][row1] = d1.x; tB_km[kbase + 1][row1] = d1.y;
    tB_km[kbase + 2][row1] = d1.z; tB_km[kbase + 3][row1] = d1.w;
    __syncthreads();
#pragma unroll 8
    for (int kk = 0; kk < KT; kk++) {
      float4 s4 = *(const float4*)&s_km[kk][ty * 4];
      float4 t4 = *(const float4*)&tA_km[kk][tx * 4];
      float4 u4 = *(const float4*)&tB_km[kk][tx * 4];
      float sv[4], tv[4], uv[4];
      unpack4(s4, sv); unpack4(t4, tv); unpack4(u4, uv);
#pragma unroll
      for (int m = 0; m < 4; m++)
#pragma unroll
        for (int n = 0; n < 4; n++) {
          accA[m][n] += sv[m] * tv[n];
          accB[m][n] += sv[m] * uv[n];
        }
    }
  }

  // finalize: scale by teacher inv-norm, masked argmax, reduce over tx, atomicMax
  float invA[4], invB[4];
#pragma unroll
  for (int n = 0; n < 4; n++) {
    int tcl = tx * 4 + n;
    invA[n] = (tcl < vtA) ? invtn[gA + tcl] : 0.f;
    invB[n] = (tcl < vtB) ? invtn[gB + tcl] : 0.f;
  }
#pragma unroll
  for (int m = 0; m < 4; m++) {
    int sl = ty * 4 + m;
    unsigned long long bestA = 0ull, bestB = 0ull;
#pragma unroll
    for (int n = 0; n < 4; n++) {
      int tcl = tx * 4 + n;
      if (tcl < vtA) bestA = umax64(bestA, pack_key(accA[m][n] * invA[n], tcA0 + tcl));
      if (tcl < vtB) bestB = umax64(bestB, pack_key(accB[m][n] * invB[n], tcB0 + tcl));
    }
#pragma unroll
    for (int o = 1; o < 16; o <<= 1) {
      bestA = umax64(bestA, __shfl_xor(bestA, o));
      bestB = umax64(bestB, __shfl_xor(bestB, o));
    }
    if (tx == 0 && sl < vs) {
      int sr = srow_of(cat, b, base_p + sl);
      if (cat < 2) {
        atomicMax(&keys[(size_t)iA * SROWS + sr], umax64(bestA, bestB));
      } else {
        atomicMax(&keys[sr], bestA);
        atomicMax(&keys[(size_t)SROWS + sr], bestB);
      }
    }
  }
}

// ---------- K3: region cross-entropy (one block per student region row) ----------
__global__ __launch_bounds__(256) void k_region(const float* __restrict__ sreg,
                                                const float* __restrict__ treg,
                                                const float* __restrict__ cgrid,
                                                const unsigned long long* __restrict__ keys,
                                                const float2* __restrict__ tstat,
                                                const int* __restrict__ epoch,
                                                float* __restrict__ partials) {
  __shared__ float sc[8];
  int r = blockIdx.x, tid = threadIdx.x;
  int j, rem;
  if (r < TCHUNK)          { j = 0; rem = r; }
  else if (r < 2 * TCHUNK) { j = 1; rem = r - TCHUNK; }
  else { int q = r - 2 * TCHUNK; j = 2 + q / LCHUNK; rem = q - (j - 2) * LCHUNK; }
  int S = (j < 2) ? NG : NL;
  int b = rem / S;
  float invt = get_invtemp(epoch);

  // student row -> regs, scaled by 1/0.1
  const float4* sp = (const float4*)(sreg + (size_t)r * D);
  float sv[16];
  unpack4(sp[tid], sv); unpack4(sp[tid + 256], sv + 4);
  unpack4(sp[tid + 512], sv + 8); unpack4(sp[tid + 768], sv + 12);
#pragma unroll
  for (int k = 0; k < 16; k++) sv[k] *= 10.f;

  float m = -INFINITY;
#pragma unroll
  for (int k = 0; k < 16; k++) m = fmaxf(m, sv[k]);
  float M = block_max(m, sc);
  float e = 0.f;
#pragma unroll
  for (int k = 0; k < 16; k++) e += expf(sv[k] - M);
  float Ssum = block_sum(e, sc);
  float base = M + logf(Ssum);

  const float4* cp = (const float4*)cgrid;
  float cv[16];
  unpack4(cp[tid], cv); unpack4(cp[tid + 256], cv + 4);
  unpack4(cp[tid + 512], cv + 8); unpack4(cp[tid + 768], cv + 12);

  float wsel = 0.5f / (float)(S * NB * 18);
  float acc;
  if (j < 2) {
    int i0 = (j == 0) ? 1 : 0;
    unsigned long long kv = keys[(size_t)i0 * SROWS + r];
    int ind = (int)(0xFFFFFFFFu - (unsigned)(kv & 0xFFFFFFFFull));
    int trow = i0 * TCHUNK + b * NG + ind;
    float2 st = tstat[trow];
    const float4* tp = (const float4*)(treg + (size_t)trow * D);
    float tv[16];
    unpack4(tp[tid], tv); unpack4(tp[tid + 256], tv + 4);
    unpack4(tp[tid + 512], tv + 8); unpack4(tp[tid + 768], tv + 12);
    float d = 0.f;
#pragma unroll
    for (int k = 0; k < 16; k++)
      d += expf((tv[k] - cv[k]) * invt - st.x) * sv[k];
    float ed = block_sum(d, sc);
    acc = wsel * (base - ed / st.y);
  } else {
    unsigned long long kv0 = keys[r];
    unsigned long long kv1 = keys[(size_t)SROWS + r];
    int ind0 = (int)(0xFFFFFFFFu - (unsigned)(kv0 & 0xFFFFFFFFull));
    int ind1 = (int)(0xFFFFFFFFu - (unsigned)(kv1 & 0xFFFFFFFFull));
    int trow0 = b * NG + ind0;
    int trow1 = TCHUNK + b * NG + ind1;
    float2 st0 = tstat[trow0];
    float2 st1 = tstat[trow1];
    const float4* tp0 = (const float4*)(treg + (size_t)trow0 * D);
    const float4* tp1 = (const float4*)(treg + (size_t)trow1 * D);
    float tv0[16], tv1[16];
    unpack4(tp0[tid], tv0); unpack4(tp1[tid], tv1);
    unpack4(tp0[tid + 256], tv0 + 4); unpack4(tp1[tid + 256], tv1 + 4);
    unpack4(tp0[tid + 512], tv0 + 8); unpack4(tp1[tid + 512], tv1 + 8);
    unpack4(tp0[tid + 768], tv0 + 12); unpack4(tp1[tid + 768], tv1 + 12);
    float d0 = 0.f, d1 = 0.f;
#pragma unroll
    for (int k = 0; k < 16; k++) {
      d0 += expf((tv0[k] - cv[k]) * invt - st0.x) * sv[k];
      d1 += expf((tv1[k] - cv[k]) * invt - st1.x) * sv[k];
    }
    float ed0, ed1;
    block_sum2(d0, d1, sc, &ed0, &ed1);
    acc = wsel * ((base - ed0 / st0.y) + (base - ed1 / st1.y));
  }
  if (tid == 0) partials[r] = acc;
}

// ---------- K4: cls cross-entropy (one block per (pair, b)) ----------
__global__ __launch_bounds__(256) void k_cls(const float* __restrict__ scls,
                                             const float* __restrict__ tcls,
                                             const float* __restrict__ center,
                                             const int* __restrict__ epoch,
                                             float* __restrict__ part) {
  __shared__ float sc[8];
  int bid = blockIdx.x, tid = threadIdx.x;
  int p = bid >> 5, b = bid & 31;
  int i = p / 9, jj = p % 9;
  int j = (jj < i) ? jj : jj + 1;
  float invtemp = get_invtemp(epoch);

  const float4* sp = (const float4*)(scls + (size_t)(j * NB + b) * D);
  float sv[16];
  unpack4(sp[tid], sv); unpack4(sp[tid + 256], sv + 4);
  unpack4(sp[tid + 512], sv + 8); unpack4(sp[tid + 768], sv + 12);
#pragma unroll
  for (int k = 0; k < 16; k++) sv[k] *= 10.f;
  float m = -INFINITY;
#pragma unroll
  for (int k = 0; k < 16; k++) m = fmaxf(m, sv[k]);
  float M = block_max(m, sc);
  float e = 0.f;
#pragma unroll
  for (int k = 0; k < 16; k++) e += expf(sv[k] - M);
  float Ssum = block_sum(e, sc);
  float base = M + logf(Ssum);

  const float4* cp = (const float4*)center;
  const float4* tp = (const float4*)(tcls + (size_t)(i * NB + b) * D);
  float tv[16], cv[16];
  unpack4(cp[tid], cv); unpack4(cp[tid + 256], cv + 4);
  unpack4(cp[tid + 512], cv + 8); unpack4(cp[tid + 768], cv + 12);
  unpack4(tp[tid], tv); unpack4(tp[tid + 256], tv + 4);
  unpack4(tp[tid + 512], tv + 8); unpack4(tp[tid + 768], tv + 12);
#pragma unroll
  for (int k = 0; k < 16; k++) tv[k] = (tv[k] - cv[k]) * invtemp;
  float tm = -INFINITY;
#pragma unroll
  for (int k = 0; k < 16; k++) tm = fmaxf(tm, tv[k]);
  float Tm = block_max(tm, sc);
  float es = 0.f, ed = 0.f;
#pragma unroll
  for (int k = 0; k < 16; k++) {
    float ee = expf(tv[k] - Tm);
    es += ee; ed += ee * sv[k];
  }
  es = block_sum(es, sc);
  ed = block_sum(ed, sc);
  if (tid == 0) part[bid] = (base - ed / es) * (0.5f / 576.f);
}

// ---------- K5: deterministic final reduce ----------
__global__ __launch_bounds__(1024) void k_final(const float* __restrict__ partials,
                                                float* __restrict__ out, int n) {
  __shared__ float sc[16];
  int tid = threadIdx.x;
  float s = 0.f;
  for (int idx = tid; idx < n; idx += 1024) s += partials[idx];
  s = warp_sum(s);
  if ((tid & 63) == 0) sc[tid >> 6] = s;
  __syncthreads();
  if (tid < 64) {
    float v = (tid < 16) ? sc[tid] : 0.f;
    v = warp_sum(v);
    if (tid == 0) out[0] = v;
  }
}

extern "C" void kernel_launch(void* const* d_in, const int* in_sizes, int n_in,
                              void* d_out, int out_size, void* d_ws, size_t ws_size,
                              hipStream_t stream) {
  const float* s_cls = (const float*)d_in[0];
  const float* s_reg = (const float*)d_in[1];
  const float* s_fea = (const float*)d_in[2];
  const float* t_cls = (const float*)d_in[3];
  const float* t_reg = (const float*)d_in[4];
  const float* t_fea = (const float*)d_in[5];
  const float* center = (const float*)d_in[6];
  const float* cgrid = (const float*)d_in[7];
  const int* epoch = (const int*)d_in[8];

  char* ws = (char*)d_ws;
  unsigned long long* keys = (unsigned long long*)ws;       // 2*21760*8 = 348160 B
  float* invtn = (float*)(ws + 348160);                     // 12544*4  = 50176 B
  float2* tstat = (float2*)(ws + 398336);                   // 12544*8  = 100352 B
  float* partials = (float*)(ws + 498688);                  // 22336*4  = 89344 B

  hipMemsetAsync(keys, 0, (size_t)2 * SROWS * sizeof(unsigned long long), stream);
  k_tnorm<<<TROWS / 4, 256, 0, stream>>>(t_fea, invtn);
  k_tstat<<<TROWS, 256, 0, stream>>>(t_reg, cgrid, epoch, tstat);
  k_sim<<<32 * 36, 256, 0, stream>>>(s_fea, t_fea, invtn, keys);
  k_region<<<SROWS, 256, 0, stream>>>(s_reg, t_reg, cgrid, keys, tstat, epoch, partials);
  k_cls<<<576, 256, 0, stream>>>(s_cls, t_cls, center, epoch, partials + SROWS);
  k_final<<<1, 1024, 0, stream>>>(partials, (float*)d_out, NPART);
}